// Round 6
// baseline (331.069 us; speedup 1.0000x reference)
//
#include <hip/hip_runtime.h>
#include <math.h>

// out[c,i] = W[i]^2 * sum_{e: iInd[e]=i} x[c, jInd[e]]   (B=1, C=32)
//
// Pipeline:
//  1. transpose x [C,N] -> xtb [N,C] in BF16 (3.2MB: fits per-XCD 4MB L2,
//     and one record's 32-channel gather = one 64B cache line).
//  2. bin_edges: LDS-staged binning of (i&127,j) records into NB buckets,
//     coalesced run flushes (one int atomic per bucket-tile).
//  3. accumulate2: NB*SPLIT blocks, 8 groups x 32 lanes (lane=channel),
//     8-deep unrolled 64B bf16 gathers -> f32 LDS accumulation. Flush
//     partials coalesced (no atomics) or w^2-scaled global atomics.
//  4. reduce_partial: sum SPLIT partials, apply W^2, add into out.
// Overflows fall back to direct f32 global atomics into out (pre-zeroed).

#define TCH 32
#define BSHIFT 7
#define BNODES 128
#define MAXNB 512
#define SLOTS 32
#define BIN_THREADS 512
#define TILE 4096
#define EPT (TILE / BIN_THREADS)
#define ACC_THREADS 256
#define UNR 8

__device__ __forceinline__ unsigned short f32_to_bf16(float f) {
    unsigned int u = __float_as_uint(f);
    unsigned int r = (u + 0x7FFFu + ((u >> 16) & 1u)) >> 16;
    return (unsigned short)r;
}
__device__ __forceinline__ float bf16_to_f32(unsigned short h) {
    return __uint_as_float(((unsigned int)h) << 16);
}

__global__ void transpose_CN_to_NC_bf16(const float* __restrict__ x,
                                        unsigned short* __restrict__ xtb,
                                        int N) {
    __shared__ float tile[32][33];
    const int n0 = blockIdx.x * 32;
    const int tx = threadIdx.x;
    const int ty = threadIdx.y;
    const int n = n0 + tx;
    if (n < N) tile[ty][tx] = x[(size_t)ty * N + n];
    __syncthreads();
    const int nw = n0 + ty;
    if (nw < N) xtb[(size_t)nw * TCH + tx] = f32_to_bf16(tile[tx][ty]);
}

__device__ __forceinline__ void direct_update(float* out, const float* W,
                                              const float* x, int i, int j,
                                              int N) {
    const float w = W[i];
    const float w2 = w * w;
    for (int c = 0; c < TCH; ++c)
        atomicAdd(&out[(size_t)c * N + i], w2 * x[(size_t)c * N + j]);
}

__global__ __launch_bounds__(BIN_THREADS) void bin_edges(
    const int* __restrict__ iInd, const int* __restrict__ jInd,
    const float* __restrict__ W, const float* __restrict__ x,
    int* __restrict__ bins, int* __restrict__ gcursor,
    float* __restrict__ out, int E, int N, int NB, int cap) {
    __shared__ int stage[MAXNB * SLOTS];  // 64 KB
    __shared__ int scnt[MAXNB];
    __shared__ int incl[MAXNB];
    __shared__ int cntA[MAXNB];
    __shared__ int gbase[MAXNB];
    const int tid = threadIdx.x;

    scnt[tid] = 0;  // BIN_THREADS == MAXNB
    __syncthreads();

    const int e0 = blockIdx.x * TILE;
    for (int s = 0; s < EPT; ++s) {
        const int e = e0 + s * BIN_THREADS + tid;
        if (e < E) {
            const int i = iInd[e];
            const int j = jInd[e];
            const int b = i >> BSHIFT;
            const int slot = atomicAdd(&scnt[b], 1);
            if (slot < SLOTS) {
                stage[b * SLOTS + slot] = ((i & (BNODES - 1)) << 16) | j;
            } else {
                direct_update(out, W, x, i, j, N);  // ultra-rare
            }
        }
    }
    __syncthreads();

    int c_b = (tid < NB) ? min(scnt[tid], SLOTS) : 0;
    cntA[tid] = c_b;
    incl[tid] = c_b;
    __syncthreads();
    for (int off = 1; off < MAXNB; off <<= 1) {
        const int v = (tid >= off) ? incl[tid - off] : 0;
        __syncthreads();
        incl[tid] += v;
        __syncthreads();
    }
    if (tid < NB && c_b > 0) gbase[tid] = atomicAdd(&gcursor[tid], c_b);
    __syncthreads();

    const int total = incl[MAXNB - 1];
    for (int idx = tid; idx < total; idx += BIN_THREADS) {
        int lo = 0, hi = MAXNB - 1;
        while (lo < hi) {
            const int mid = (lo + hi) >> 1;
            if (incl[mid] > idx) hi = mid; else lo = mid + 1;
        }
        const int b = lo;
        const int k = idx - (incl[b] - cntA[b]);
        const int rec = stage[b * SLOTS + k];
        const int gslot = gbase[b] + k;
        if (gslot < cap) {
            bins[(size_t)b * cap + gslot] = rec;
        } else {
            const int i = (b << BSHIFT) | (rec >> 16);
            direct_update(out, W, x, i, rec & 0xFFFF, N);  // ultra-rare
        }
    }
}

// NB*SPLIT blocks; block = 8 groups x 32 lanes. lane = channel.
__global__ __launch_bounds__(ACC_THREADS) void accumulate2(
    const int* __restrict__ bins, const int* __restrict__ gcursor,
    const unsigned short* __restrict__ xtb, const float* __restrict__ W,
    float* __restrict__ partial, float* __restrict__ out,
    int N, int cap, int SPLIT, int use_partial) {
    const int bucket = blockIdx.x / SPLIT;
    const int split  = blockIdx.x - bucket * SPLIT;
    __shared__ float acc[BNODES * 33];
    for (int k = threadIdx.x; k < BNODES * 33; k += ACC_THREADS) acc[k] = 0.f;
    __syncthreads();

    int cnt = gcursor[bucket];
    if (cnt > cap) cnt = cap;
    const int* rec = bins + (size_t)bucket * cap;
    const int chunk = (cnt + SPLIT - 1) / SPLIT;
    const int r0 = split * chunk;
    const int r1 = min(cnt, r0 + chunk);

    const int c = threadIdx.x & 31;      // channel
    const int g = threadIdx.x >> 5;      // group 0..7
    const int stride = ACC_THREADS / 32; // 8

    int r = r0 + g;
    for (; r + (UNR - 1) * stride < r1; r += UNR * stride) {
        int pr0 = __builtin_nontemporal_load(&rec[r + 0 * stride]);
        int pr1 = __builtin_nontemporal_load(&rec[r + 1 * stride]);
        int pr2 = __builtin_nontemporal_load(&rec[r + 2 * stride]);
        int pr3 = __builtin_nontemporal_load(&rec[r + 3 * stride]);
        int pr4 = __builtin_nontemporal_load(&rec[r + 4 * stride]);
        int pr5 = __builtin_nontemporal_load(&rec[r + 5 * stride]);
        int pr6 = __builtin_nontemporal_load(&rec[r + 6 * stride]);
        int pr7 = __builtin_nontemporal_load(&rec[r + 7 * stride]);
        float v0 = bf16_to_f32(xtb[(size_t)(pr0 & 0xFFFF) * TCH + c]);
        float v1 = bf16_to_f32(xtb[(size_t)(pr1 & 0xFFFF) * TCH + c]);
        float v2 = bf16_to_f32(xtb[(size_t)(pr2 & 0xFFFF) * TCH + c]);
        float v3 = bf16_to_f32(xtb[(size_t)(pr3 & 0xFFFF) * TCH + c]);
        float v4 = bf16_to_f32(xtb[(size_t)(pr4 & 0xFFFF) * TCH + c]);
        float v5 = bf16_to_f32(xtb[(size_t)(pr5 & 0xFFFF) * TCH + c]);
        float v6 = bf16_to_f32(xtb[(size_t)(pr6 & 0xFFFF) * TCH + c]);
        float v7 = bf16_to_f32(xtb[(size_t)(pr7 & 0xFFFF) * TCH + c]);
        atomicAdd(&acc[(pr0 >> 16) * 33 + c], v0);
        atomicAdd(&acc[(pr1 >> 16) * 33 + c], v1);
        atomicAdd(&acc[(pr2 >> 16) * 33 + c], v2);
        atomicAdd(&acc[(pr3 >> 16) * 33 + c], v3);
        atomicAdd(&acc[(pr4 >> 16) * 33 + c], v4);
        atomicAdd(&acc[(pr5 >> 16) * 33 + c], v5);
        atomicAdd(&acc[(pr6 >> 16) * 33 + c], v6);
        atomicAdd(&acc[(pr7 >> 16) * 33 + c], v7);
    }
    for (; r < r1; r += stride) {
        const int pr = __builtin_nontemporal_load(&rec[r]);
        atomicAdd(&acc[(pr >> 16) * 33 + c],
                  bf16_to_f32(xtb[(size_t)(pr & 0xFFFF) * TCH + c]));
    }
    __syncthreads();

    if (use_partial) {
        float* p = partial + (size_t)blockIdx.x * (BNODES * TCH);
        for (int k = threadIdx.x; k < BNODES * TCH; k += ACC_THREADS) {
            const int il = k & (BNODES - 1);
            const int cc = k >> BSHIFT;
            p[k] = acc[il * 33 + cc];  // [c][il] layout, coalesced
        }
    } else {
        const int i0 = bucket << BSHIFT;
        for (int k = threadIdx.x; k < BNODES * TCH; k += ACC_THREADS) {
            const int il = k & (BNODES - 1);
            const int cc = k >> BSHIFT;
            const int i = i0 + il;
            if (i < N) {
                const float v = acc[il * 33 + cc];
                if (v != 0.f) {
                    const float w = W[i];
                    atomicAdd(&out[(size_t)cc * N + i], w * w * v);
                }
            }
        }
    }
}

// grid: ((N+255)/256, 32); adds W^2 * sum(partials) into out.
__global__ void reduce_partial(const float* __restrict__ partial,
                               const float* __restrict__ W,
                               float* __restrict__ out, int N, int SPLIT) {
    const int i = blockIdx.x * 256 + threadIdx.x;
    const int c = blockIdx.y;
    if (i >= N) return;
    const int bucket = i >> BSHIFT;
    const int il = i & (BNODES - 1);
    const float* p = partial + (size_t)bucket * SPLIT * (BNODES * TCH)
                             + (size_t)c * BNODES + il;
    float s = 0.f;
    for (int sp = 0; sp < SPLIT; ++sp) s += p[(size_t)sp * (BNODES * TCH)];
    const float w = W[i];
    out[(size_t)c * N + i] += w * w * s;
}

// ---- fallback (ws too small / N too big for record packing) ----
__global__ void edge_scatter_cn(const int* __restrict__ iInd,
                                const int* __restrict__ jInd,
                                const float* __restrict__ W,
                                const float* __restrict__ x,
                                float* __restrict__ out, int E, int N) {
    const long long t = (long long)blockIdx.x * blockDim.x + threadIdx.x;
    const int e = (int)(t >> 5);
    const int c = (int)(t & 31);
    if (e < E) {
        const int i = iInd[e];
        const int j = jInd[e];
        const float w = W[i];
        atomicAdd(&out[(size_t)c * N + i], w * w * x[(size_t)c * N + j]);
    }
}

extern "C" void kernel_launch(void* const* d_in, const int* in_sizes, int n_in,
                              void* d_out, int out_size, void* d_ws, size_t ws_size,
                              hipStream_t stream) {
    const float* x    = (const float*)d_in[0];   // [1, C, N]
    const float* W    = (const float*)d_in[1];   // [N]
    const int*   iInd = (const int*)d_in[2];     // [E]
    const int*   jInd = (const int*)d_in[3];     // [E]

    const int N = in_sizes[1];
    const int E = in_sizes[2];
    float* out = (float*)d_out;

    const int NB = (N + BNODES - 1) >> BSHIFT;
    const int mean = (NB > 0) ? (E / NB) : 0;
    const int cap = mean + (int)(8.0 * sqrt((double)(mean > 0 ? mean : 1))) + 64;

    // byte-layout in ws, 256B-aligned sections
    const size_t A = 256;
    const size_t xtb_bytes = (((size_t)N * TCH * 2) + A - 1) / A * A;
    const size_t bin_bytes = (((size_t)NB * cap * 4) + A - 1) / A * A;
    const size_t cur_bytes = (((size_t)NB * 4) + A - 1) / A * A;
    const size_t base_need = xtb_bytes + bin_bytes + cur_bytes;

    if (ws_size >= base_need && NB <= MAXNB && N <= 65536) {
        char* wsb = (char*)d_ws;
        unsigned short* xtb = (unsigned short*)wsb;
        int*   bins    = (int*)(wsb + xtb_bytes);
        int*   gcursor = (int*)(wsb + xtb_bytes + bin_bytes);
        float* partial = (float*)(wsb + base_need);

        int SPLIT = 8, use_partial = 0;
        for (int s = 8; s >= 2; s >>= 1) {
            const size_t pb = (size_t)NB * s * BNODES * TCH * 4;
            if (base_need + pb <= ws_size) {
                SPLIT = s; use_partial = 1; break;
            }
        }

        hipMemsetAsync(out, 0, (size_t)out_size * sizeof(float), stream);
        hipMemsetAsync(gcursor, 0, (size_t)NB * sizeof(int), stream);

        const int ntiles = (N + 31) / 32;
        dim3 tb(32, 32);
        transpose_CN_to_NC_bf16<<<ntiles, tb, 0, stream>>>(x, xtb, N);

        const int bin_blocks = (E + TILE - 1) / TILE;
        bin_edges<<<bin_blocks, BIN_THREADS, 0, stream>>>(
            iInd, jInd, W, x, bins, gcursor, out, E, N, NB, cap);

        accumulate2<<<NB * SPLIT, ACC_THREADS, 0, stream>>>(
            bins, gcursor, xtb, W, partial, out, N, cap, SPLIT, use_partial);

        if (use_partial) {
            dim3 rg((N + 255) / 256, TCH);
            reduce_partial<<<rg, 256, 0, stream>>>(partial, W, out, N, SPLIT);
        }
    } else {
        hipMemsetAsync(out, 0, (size_t)out_size * sizeof(float), stream);
        const int threads = 256;
        const long long total = (long long)E * TCH;
        const int blocks = (int)((total + threads - 1) / threads);
        edge_scatter_cn<<<blocks, threads, 0, stream>>>(iInd, jInd, W, x, out, E, N);
    }
}